// Round 1
// baseline (470.533 us; speedup 1.0000x reference)
//
#include <hip/hip_runtime.h>
#include <hip/hip_bf16.h>

#define B_ 4096
#define T_ 4
#define D_ 1024
#define E_ 4

typedef unsigned short ushort_t;
typedef float f32x4 __attribute__((ext_vector_type(4)));
typedef short bf16x8 __attribute__((ext_vector_type(8)));

__device__ __forceinline__ unsigned short f2bf(float f) {
    unsigned int u = __float_as_uint(f);
    u += 0x7FFF + ((u >> 16) & 1);   // round-to-nearest-even
    return (unsigned short)(u >> 16);
}

#define GLOBAL_LOAD_LDS16(gp, lp)                                                        \
    __builtin_amdgcn_global_load_lds((const __attribute__((address_space(1))) void*)(gp),\
                                     (__attribute__((address_space(3))) void*)(lp),      \
                                     16, 0, 0)

// x [B,T,D] f32 -> Hbf [T,B,D] bf16
__global__ __launch_bounds__(256) void k_convert_x(const float* __restrict__ x,
                                                   ushort_t* __restrict__ hbf) {
    int idx = (blockIdx.x * 256 + threadIdx.x) * 4;
    int d = idx & (D_ - 1);
    int t = (idx >> 10) & 3;
    int b = idx >> 12;
    const float4 v = *(const float4*)(x + idx);
    ushort4 o = { f2bf(v.x), f2bf(v.y), f2bf(v.z), f2bf(v.w) };
    *(ushort4*)(hbf + (size_t)t * B_ * D_ + (size_t)b * D_ + d) = o;
}

// W [8, D, O] f32 -> Wt [8, O, D] bf16   (8 = L*T matrices)
__global__ __launch_bounds__(256) void k_transpose_w(const float* __restrict__ W,
                                                     ushort_t* __restrict__ Wt) {
    __shared__ float tile[32][33];
    const int z = blockIdx.z;
    const float* src = W + (size_t)z * D_ * D_;
    ushort_t* dst = Wt + (size_t)z * D_ * D_;
    const int o0 = blockIdx.x * 32, d0 = blockIdx.y * 32;
    const int tx = threadIdx.x, ty = threadIdx.y;  // 32 x 8
#pragma unroll
    for (int j = 0; j < 4; ++j)
        tile[ty + 8 * j][tx] = src[(size_t)(d0 + ty + 8 * j) * D_ + o0 + tx];
    __syncthreads();
#pragma unroll
    for (int j = 0; j < 4; ++j)
        dst[(size_t)(o0 + ty + 8 * j) * D_ + d0 + tx] = f2bf(tile[tx][ty + 8 * j]);
}

// C[4096,1024] = relu(A * Bt^T + bias) [* scale], batched over tasks (blockIdx.z)
// A  : [T, 4096, 1024] bf16 (row-major, k contiguous)
// Bt : [T, 1024, 1024] bf16 (N-major: row n holds W[:,n], k contiguous)
template <bool OUT_BF16>
__global__ __launch_bounds__(256) void k_gemm_bt(
    const ushort_t* __restrict__ A,
    const ushort_t* __restrict__ Bt,
    const float* __restrict__ bias,   // [T, 1024]
    void* __restrict__ out,           // [T, 4096, 1024]
    const float* __restrict__ inte)   // [T, E] or null
{
    const int t = blockIdx.z;
    const ushort_t* Ap = A + (size_t)t * B_ * D_;
    const ushort_t* Bp = Bt + (size_t)t * D_ * D_;
    const float* bp = bias + t * D_;
    const int m0 = blockIdx.y * 128, n0 = blockIdx.x * 128;

    __shared__ __align__(16) ushort_t As[128 * 32];
    __shared__ __align__(16) ushort_t Bs[128 * 32];

    const int tid = threadIdx.x;
    const int lane = tid & 63, wid = tid >> 6;
    const int lr = lane & 15, quad = lane >> 4;
    const int wm = (wid & 1) * 64, wn = (wid >> 1) * 64;

    f32x4 acc[4][4] = {};

    // staging: 512 16B-chunks per tile; wave w, inst i covers chunks w*128+i*64+lane
    const int q0 = wid * 128 + lane;
    const int q1 = q0 + 64;
    ushort_t* asb0 = As + wid * 1024;
    ushort_t* asb1 = As + wid * 1024 + 512;
    ushort_t* bsb0 = Bs + wid * 1024;
    ushort_t* bsb1 = Bs + wid * 1024 + 512;
    const ushort_t* ga0 = Ap + (size_t)(m0 + (q0 >> 2)) * D_ + (q0 & 3) * 8;
    const ushort_t* ga1 = Ap + (size_t)(m0 + (q1 >> 2)) * D_ + (q1 & 3) * 8;
    const ushort_t* gb0 = Bp + (size_t)(n0 + (q0 >> 2)) * D_ + (q0 & 3) * 8;
    const ushort_t* gb1 = Bp + (size_t)(n0 + (q1 >> 2)) * D_ + (q1 & 3) * 8;

    for (int k0 = 0; k0 < D_; k0 += 32) {
        GLOBAL_LOAD_LDS16(ga0 + k0, asb0);
        GLOBAL_LOAD_LDS16(ga1 + k0, asb1);
        GLOBAL_LOAD_LDS16(gb0 + k0, bsb0);
        GLOBAL_LOAD_LDS16(gb1 + k0, bsb1);
        __syncthreads();
        bf16x8 af[4], bfv[4];
#pragma unroll
        for (int mi = 0; mi < 4; ++mi)
            af[mi] = *(const bf16x8*)(As + (wm + mi * 16 + lr) * 32 + quad * 8);
#pragma unroll
        for (int ni = 0; ni < 4; ++ni)
            bfv[ni] = *(const bf16x8*)(Bs + (wn + ni * 16 + lr) * 32 + quad * 8);
#pragma unroll
        for (int mi = 0; mi < 4; ++mi)
#pragma unroll
            for (int ni = 0; ni < 4; ++ni)
                acc[mi][ni] = __builtin_amdgcn_mfma_f32_16x16x32_bf16(
                    af[mi], bfv[ni], acc[mi][ni], 0, 0, 0);
        __syncthreads();
    }

    float scale = 1.0f;
    if (inte) {
        const float* ip = inte + t * E_;
        scale = ip[0] + ip[1] + ip[2] + ip[3];
    }
#pragma unroll
    for (int mi = 0; mi < 4; ++mi) {
#pragma unroll
        for (int ni = 0; ni < 4; ++ni) {
            const int gcol = n0 + wn + ni * 16 + lr;
            const float bv = bp[gcol];
#pragma unroll
            for (int r = 0; r < 4; ++r) {
                const int grow = m0 + wm + mi * 16 + quad * 4 + r;
                float v = acc[mi][ni][r] + bv;
                v = fmaxf(v, 0.0f) * scale;
                const size_t off = (size_t)t * B_ * D_ + (size_t)grow * D_ + gcol;
                if (OUT_BF16) ((ushort_t*)out)[off] = f2bf(v);
                else          ((float*)out)[off] = v;
            }
        }
    }
}

// gate + combine: one block per batch row b
template <bool FINAL>
__global__ __launch_bounds__(256) void k_gate_combine(
    const float* __restrict__ teo,  // [T, B, D] f32
    const float* __restrict__ Wg,   // [D, T] f32
    const float* __restrict__ bg,   // [T] f32
    void* __restrict__ out)         // FINAL: f32 [B,T,D]; else bf16 [T,B,D]
{
    const int b = blockIdx.x;
    const int tid = threadIdx.x;
    const int d0 = tid * 4;
    const int lane = tid & 63, wid = tid >> 6;

    float4 tv[4];
#pragma unroll
    for (int t = 0; t < 4; ++t)
        tv[t] = *(const float4*)(teo + (size_t)t * B_ * D_ + (size_t)b * D_ + d0);
    float4 wg[4];
#pragma unroll
    for (int i = 0; i < 4; ++i)
        wg[i] = *(const float4*)(Wg + (size_t)(d0 + i) * 4);

    float p[16];
#pragma unroll
    for (int t = 0; t < 4; ++t) {
        const float* tvp = (const float*)&tv[t];
#pragma unroll
        for (int k = 0; k < 4; ++k) {
            p[t * 4 + k] = tvp[0] * ((const float*)&wg[0])[k]
                         + tvp[1] * ((const float*)&wg[1])[k]
                         + tvp[2] * ((const float*)&wg[2])[k]
                         + tvp[3] * ((const float*)&wg[3])[k];
        }
    }
#pragma unroll
    for (int i = 0; i < 16; ++i) {
        float v = p[i];
#pragma unroll
        for (int off = 32; off > 0; off >>= 1)
            v += __shfl_xor(v, off, 64);
        p[i] = v;
    }
    __shared__ float red[4][16];
    if (lane == 0) {
#pragma unroll
        for (int i = 0; i < 16; ++i) red[wid][i] = p[i];
    }
    __syncthreads();

    float g[4][4];
#pragma unroll
    for (int t = 0; t < 4; ++t) {
        float lg[4];
#pragma unroll
        for (int k = 0; k < 4; ++k)
            lg[k] = red[0][t * 4 + k] + red[1][t * 4 + k] + red[2][t * 4 + k]
                  + red[3][t * 4 + k] + bg[k];
        float mx = fmaxf(fmaxf(lg[0], lg[1]), fmaxf(lg[2], lg[3]));
        float e0 = __expf(lg[0] - mx), e1 = __expf(lg[1] - mx);
        float e2 = __expf(lg[2] - mx), e3 = __expf(lg[3] - mx);
        float inv = 1.0f / (e0 + e1 + e2 + e3);
        g[t][0] = e0 * inv; g[t][1] = e1 * inv; g[t][2] = e2 * inv; g[t][3] = e3 * inv;
    }
#pragma unroll
    for (int t = 0; t < 4; ++t) {
        float o[4];
#pragma unroll
        for (int i = 0; i < 4; ++i) {
            o[i] = g[t][0] * ((const float*)&tv[0])[i]
                 + g[t][1] * ((const float*)&tv[1])[i]
                 + g[t][2] * ((const float*)&tv[2])[i]
                 + g[t][3] * ((const float*)&tv[3])[i]
                 + ((const float*)&tv[t])[i];
        }
        if (FINAL) {
            float4 ov = { o[0], o[1], o[2], o[3] };
            *(float4*)((float*)out + (size_t)b * T_ * D_ + (size_t)t * D_ + d0) = ov;
        } else {
            ushort4 ov = { f2bf(o[0]), f2bf(o[1]), f2bf(o[2]), f2bf(o[3]) };
            *(ushort4*)((ushort_t*)out + (size_t)t * B_ * D_ + (size_t)b * D_ + d0) = ov;
        }
    }
}

extern "C" void kernel_launch(void* const* d_in, const int* in_sizes, int n_in,
                              void* d_out, int out_size, void* d_ws, size_t ws_size,
                              hipStream_t stream) {
    const float* x    = (const float*)d_in[0];
    const float* W1   = (const float*)d_in[1];
    const float* b1   = (const float*)d_in[2];
    const float* W2   = (const float*)d_in[3];
    const float* b2   = (const float*)d_in[4];
    const float* inte = (const float*)d_in[5];
    const float* Wg   = (const float*)d_in[6];
    const float* bg   = (const float*)d_in[7];

    char* ws = (char*)d_ws;
    // ws layout (bytes): W1t 32M | W2t 32M | Hbf 32M | T1bf 32M | Teo 64M = 192 MiB
    ushort_t* W1t  = (ushort_t*)(ws);
    ushort_t* W2t  = (ushort_t*)(ws + 33554432);
    ushort_t* Hbf  = (ushort_t*)(ws + 67108864);
    ushort_t* T1bf = (ushort_t*)(ws + 100663296);
    float*    Teo  = (float*)   (ws + 134217728);

    k_convert_x<<<dim3(B_ * T_ * D_ / 1024), 256, 0, stream>>>(x, Hbf);
    dim3 tg(D_ / 32, D_ / 32, 8);
    k_transpose_w<<<tg, dim3(32, 8), 0, stream>>>(W1, W1t);
    k_transpose_w<<<tg, dim3(32, 8), 0, stream>>>(W2, W2t);

    dim3 gg(D_ / 128, B_ / 128, T_);
    for (int l = 0; l < 2; ++l) {
        const size_t wOff = (size_t)l * T_ * D_ * D_;
        k_gemm_bt<true ><<<gg, 256, 0, stream>>>(Hbf, W1t + wOff, b1 + l * T_ * D_,
                                                 (void*)T1bf, nullptr);
        k_gemm_bt<false><<<gg, 256, 0, stream>>>(T1bf, W2t + wOff, b2 + l * T_ * D_,
                                                 (void*)Teo, inte + l * T_ * E_);
        if (l == 0)
            k_gate_combine<false><<<dim3(B_), 256, 0, stream>>>(
                Teo, Wg + l * D_ * T_, bg + l * T_, (void*)Hbf);
        else
            k_gate_combine<true ><<<dim3(B_), 256, 0, stream>>>(
                Teo, Wg + l * D_ * T_, bg + l * T_, (void*)d_out);
    }
}

// Round 2
// 451.357 us; speedup vs baseline: 1.0425x; 1.0425x over previous
//
#include <hip/hip_runtime.h>
#include <hip/hip_bf16.h>

#define B_ 4096
#define T_ 4
#define D_ 1024
#define E_ 4

typedef unsigned short ushort_t;
typedef float f32x4 __attribute__((ext_vector_type(4)));
typedef short bf16x8 __attribute__((ext_vector_type(8)));

__device__ __forceinline__ unsigned short f2bf(float f) {
    unsigned int u = __float_as_uint(f);
    u += 0x7FFF + ((u >> 16) & 1);   // round-to-nearest-even
    return (unsigned short)(u >> 16);
}

#define GLOBAL_LOAD_LDS16(gp, lp)                                                        \
    __builtin_amdgcn_global_load_lds((const __attribute__((address_space(1))) void*)(gp),\
                                     (__attribute__((address_space(3))) void*)(lp),      \
                                     16, 0, 0)

// x [B,T,D] f32 -> Hbf [T,B,D] bf16
__global__ __launch_bounds__(256) void k_convert_x(const float* __restrict__ x,
                                                   ushort_t* __restrict__ hbf) {
    int idx = (blockIdx.x * 256 + threadIdx.x) * 4;
    int d = idx & (D_ - 1);
    int t = (idx >> 10) & 3;
    int b = idx >> 12;
    const float4 v = *(const float4*)(x + idx);
    ushort4 o = { f2bf(v.x), f2bf(v.y), f2bf(v.z), f2bf(v.w) };
    *(ushort4*)(hbf + (size_t)t * B_ * D_ + (size_t)b * D_ + d) = o;
}

// W1,W2 [8, D, O] f32 -> W1t,W2t [8, O, D] bf16 in one launch (z: 0..7=W1, 8..15=W2)
__global__ __launch_bounds__(256) void k_transpose_w(const float* __restrict__ W1,
                                                     const float* __restrict__ W2,
                                                     ushort_t* __restrict__ W1t,
                                                     ushort_t* __restrict__ W2t) {
    __shared__ float tile[32][33];
    const int z = blockIdx.z;
    const float* src = (z < 8) ? (W1 + (size_t)z * D_ * D_) : (W2 + (size_t)(z - 8) * D_ * D_);
    ushort_t* dst = (z < 8) ? (W1t + (size_t)z * D_ * D_) : (W2t + (size_t)(z - 8) * D_ * D_);
    const int o0 = blockIdx.x * 32, d0 = blockIdx.y * 32;
    const int tx = threadIdx.x, ty = threadIdx.y;  // 32 x 8
#pragma unroll
    for (int j = 0; j < 4; ++j)
        tile[ty + 8 * j][tx] = src[(size_t)(d0 + ty + 8 * j) * D_ + o0 + tx];
    __syncthreads();
#pragma unroll
    for (int j = 0; j < 4; ++j)
        dst[(size_t)(o0 + ty + 8 * j) * D_ + d0 + tx] = f2bf(tile[tx][ty + 8 * j]);
}

// C[4096,1024] = relu(A * Bt^T + bias) [* scale], batched over tasks.
// Double-buffered LDS (1 barrier/iter) + XCD-swizzled block mapping.
// A  : [T, 4096, 1024] bf16 (row-major, k contiguous)
// Bt : [T, 1024, 1024] bf16 (N-major: row n holds W[:,n], k contiguous)
template <bool OUT_BF16>
__global__ __launch_bounds__(256) void k_gemm_bt(
    const ushort_t* __restrict__ A,
    const ushort_t* __restrict__ Bt,
    const float* __restrict__ bias,   // [T, 1024]
    void* __restrict__ out,           // [T, 4096, 1024]
    const float* __restrict__ inte)   // [T, E] or null
{
    // XCD swizzle: XCD = f%8 (round-robin heuristic). All 8 n-blocks that share
    // one A row-panel get the same f%8 -> same XCD -> A fetched once per XCD.
    const int f = blockIdx.x;                 // 0..1023
    const int n_blk = (f >> 3) & 7;
    const int mt = (f & 7) | ((f >> 6) << 3); // 0..127
    const int m_blk = mt & 31;
    const int t = mt >> 5;
    const int m0 = m_blk * 128, n0 = n_blk * 128;

    const ushort_t* Ap = A + (size_t)t * B_ * D_;
    const ushort_t* Bp = Bt + (size_t)t * D_ * D_;
    const float* bp = bias + t * D_;

    __shared__ __align__(16) ushort_t As[2][128 * 32];
    __shared__ __align__(16) ushort_t Bs[2][128 * 32];

    const int tid = threadIdx.x;
    const int lane = tid & 63, wid = tid >> 6;
    const int lr = lane & 15, quad = lane >> 4;
    const int wm = (wid & 1) * 64, wn = (wid >> 1) * 64;

    f32x4 acc[4][4] = {};

    // staging: 512 16B-chunks per tile; chunk q -> row q>>2, cols (q&3)*8
    const int q0 = wid * 128 + lane;
    const int q1 = q0 + 64;
    const ushort_t* ga0 = Ap + (size_t)(m0 + (q0 >> 2)) * D_ + (q0 & 3) * 8;
    const ushort_t* ga1 = Ap + (size_t)(m0 + (q1 >> 2)) * D_ + (q1 & 3) * 8;
    const ushort_t* gb0 = Bp + (size_t)(n0 + (q0 >> 2)) * D_ + (q0 & 3) * 8;
    const ushort_t* gb1 = Bp + (size_t)(n0 + (q1 >> 2)) * D_ + (q1 & 3) * 8;

#define STAGE(k0, s)                                           \
    do {                                                       \
        GLOBAL_LOAD_LDS16(ga0 + (k0), As[s] + wid * 1024);        \
        GLOBAL_LOAD_LDS16(ga1 + (k0), As[s] + wid * 1024 + 512);  \
        GLOBAL_LOAD_LDS16(gb0 + (k0), Bs[s] + wid * 1024);        \
        GLOBAL_LOAD_LDS16(gb1 + (k0), Bs[s] + wid * 1024 + 512);  \
    } while (0)

    STAGE(0, 0);
    int s = 0;
    for (int k0 = 0; k0 < D_; k0 += 32, s ^= 1) {
        __syncthreads();                    // drains buf-s loads; prev compute done
        if (k0 + 32 < D_) STAGE(k0 + 32, s ^ 1);  // in flight during compute below
        bf16x8 af[4], bfv[4];
#pragma unroll
        for (int mi = 0; mi < 4; ++mi)
            af[mi] = *(const bf16x8*)(As[s] + (wm + mi * 16 + lr) * 32 + quad * 8);
#pragma unroll
        for (int ni = 0; ni < 4; ++ni)
            bfv[ni] = *(const bf16x8*)(Bs[s] + (wn + ni * 16 + lr) * 32 + quad * 8);
#pragma unroll
        for (int mi = 0; mi < 4; ++mi)
#pragma unroll
            for (int ni = 0; ni < 4; ++ni)
                acc[mi][ni] = __builtin_amdgcn_mfma_f32_16x16x32_bf16(
                    af[mi], bfv[ni], acc[mi][ni], 0, 0, 0);
    }
#undef STAGE

    float scale = 1.0f;
    if (inte) {
        const float* ip = inte + t * E_;
        scale = ip[0] + ip[1] + ip[2] + ip[3];
    }
#pragma unroll
    for (int mi = 0; mi < 4; ++mi) {
#pragma unroll
        for (int ni = 0; ni < 4; ++ni) {
            const int gcol = n0 + wn + ni * 16 + lr;
            const float bv = bp[gcol];
#pragma unroll
            for (int r = 0; r < 4; ++r) {
                const int grow = m0 + wm + mi * 16 + quad * 4 + r;
                float v = acc[mi][ni][r] + bv;
                v = fmaxf(v, 0.0f) * scale;
                const size_t off = (size_t)t * B_ * D_ + (size_t)grow * D_ + gcol;
                if (OUT_BF16) ((ushort_t*)out)[off] = f2bf(v);
                else          ((float*)out)[off] = v;
            }
        }
    }
}

// gate + combine: one block per batch row b
template <bool FINAL>
__global__ __launch_bounds__(256) void k_gate_combine(
    const float* __restrict__ teo,  // [T, B, D] f32
    const float* __restrict__ Wg,   // [D, T] f32
    const float* __restrict__ bg,   // [T] f32
    void* __restrict__ out)         // FINAL: f32 [B,T,D]; else bf16 [T,B,D]
{
    const int b = blockIdx.x;
    const int tid = threadIdx.x;
    const int d0 = tid * 4;

    float4 tv[4];
#pragma unroll
    for (int t = 0; t < 4; ++t)
        tv[t] = *(const float4*)(teo + (size_t)t * B_ * D_ + (size_t)b * D_ + d0);
    float4 wg[4];
#pragma unroll
    for (int i = 0; i < 4; ++i)
        wg[i] = *(const float4*)(Wg + (size_t)(d0 + i) * 4);

    float p[16];
#pragma unroll
    for (int t = 0; t < 4; ++t) {
        const float* tvp = (const float*)&tv[t];
#pragma unroll
        for (int k = 0; k < 4; ++k) {
            p[t * 4 + k] = tvp[0] * ((const float*)&wg[0])[k]
                         + tvp[1] * ((const float*)&wg[1])[k]
                         + tvp[2] * ((const float*)&wg[2])[k]
                         + tvp[3] * ((const float*)&wg[3])[k];
        }
    }
    // 4-step butterfly: sum within 16-lane groups, then 2-stage LDS combine
#pragma unroll
    for (int i = 0; i < 16; ++i) {
        float v = p[i];
        v += __shfl_xor(v, 1, 64);
        v += __shfl_xor(v, 2, 64);
        v += __shfl_xor(v, 4, 64);
        v += __shfl_xor(v, 8, 64);
        p[i] = v;
    }
    __shared__ float red[16][16];
    __shared__ float fin[16];
    const int grp = tid >> 4;
    if ((tid & 15) == 0) {
#pragma unroll
        for (int i = 0; i < 16; ++i) red[grp][i] = p[i];
    }
    __syncthreads();
    if (tid < 16) {
        float v = 0.0f;
#pragma unroll
        for (int g = 0; g < 16; ++g) v += red[g][tid];
        fin[tid] = v;
    }
    __syncthreads();

    float g[4][4];
#pragma unroll
    for (int t = 0; t < 4; ++t) {
        float lg[4];
#pragma unroll
        for (int k = 0; k < 4; ++k)
            lg[k] = fin[t * 4 + k] + bg[k];
        float mx = fmaxf(fmaxf(lg[0], lg[1]), fmaxf(lg[2], lg[3]));
        float e0 = __expf(lg[0] - mx), e1 = __expf(lg[1] - mx);
        float e2 = __expf(lg[2] - mx), e3 = __expf(lg[3] - mx);
        float inv = 1.0f / (e0 + e1 + e2 + e3);
        g[t][0] = e0 * inv; g[t][1] = e1 * inv; g[t][2] = e2 * inv; g[t][3] = e3 * inv;
    }
#pragma unroll
    for (int t = 0; t < 4; ++t) {
        float o[4];
#pragma unroll
        for (int i = 0; i < 4; ++i) {
            o[i] = g[t][0] * ((const float*)&tv[0])[i]
                 + g[t][1] * ((const float*)&tv[1])[i]
                 + g[t][2] * ((const float*)&tv[2])[i]
                 + g[t][3] * ((const float*)&tv[3])[i]
                 + ((const float*)&tv[t])[i];
        }
        if (FINAL) {
            float4 ov = { o[0], o[1], o[2], o[3] };
            *(float4*)((float*)out + (size_t)b * T_ * D_ + (size_t)t * D_ + d0) = ov;
        } else {
            ushort4 ov = { f2bf(o[0]), f2bf(o[1]), f2bf(o[2]), f2bf(o[3]) };
            *(ushort4*)((ushort_t*)out + (size_t)t * B_ * D_ + (size_t)b * D_ + d0) = ov;
        }
    }
}

extern "C" void kernel_launch(void* const* d_in, const int* in_sizes, int n_in,
                              void* d_out, int out_size, void* d_ws, size_t ws_size,
                              hipStream_t stream) {
    const float* x    = (const float*)d_in[0];
    const float* W1   = (const float*)d_in[1];
    const float* b1   = (const float*)d_in[2];
    const float* W2   = (const float*)d_in[3];
    const float* b2   = (const float*)d_in[4];
    const float* inte = (const float*)d_in[5];
    const float* Wg   = (const float*)d_in[6];
    const float* bg   = (const float*)d_in[7];

    char* ws = (char*)d_ws;
    // ws layout (bytes): W1t 32M | W2t 32M | Hbf 32M | T1bf 32M | Teo 64M = 192 MiB
    ushort_t* W1t  = (ushort_t*)(ws);
    ushort_t* W2t  = (ushort_t*)(ws + 33554432);
    ushort_t* Hbf  = (ushort_t*)(ws + 67108864);
    ushort_t* T1bf = (ushort_t*)(ws + 100663296);
    float*    Teo  = (float*)   (ws + 134217728);

    k_convert_x<<<dim3(B_ * T_ * D_ / 1024), 256, 0, stream>>>(x, Hbf);
    k_transpose_w<<<dim3(D_ / 32, D_ / 32, 16), dim3(32, 8), 0, stream>>>(W1, W2, W1t, W2t);

    for (int l = 0; l < 2; ++l) {
        const size_t wOff = (size_t)l * T_ * D_ * D_;
        k_gemm_bt<true ><<<dim3(1024), 256, 0, stream>>>(Hbf, W1t + wOff, b1 + l * T_ * D_,
                                                         (void*)T1bf, nullptr);
        k_gemm_bt<false><<<dim3(1024), 256, 0, stream>>>(T1bf, W2t + wOff, b2 + l * T_ * D_,
                                                         (void*)Teo, inte + l * T_ * E_);
        if (l == 0)
            k_gate_combine<false><<<dim3(B_), 256, 0, stream>>>(
                Teo, Wg + l * D_ * T_, bg + l * T_, (void*)Hbf);
        else
            k_gate_combine<true ><<<dim3(B_), 256, 0, stream>>>(
                Teo, Wg + l * D_ * T_, bg + l * T_, (void*)d_out);
    }
}

// Round 3
// 377.909 us; speedup vs baseline: 1.2451x; 1.1944x over previous
//
#include <hip/hip_runtime.h>
#include <hip/hip_bf16.h>

#define B_ 4096
#define T_ 4
#define D_ 1024
#define E_ 4

typedef unsigned short ushort_t;
typedef float f32x4 __attribute__((ext_vector_type(4)));
typedef short bf16x8 __attribute__((ext_vector_type(8)));

__device__ __forceinline__ unsigned short f2bf(float f) {
    unsigned int u = __float_as_uint(f);
    u += 0x7FFF + ((u >> 16) & 1);   // round-to-nearest-even
    return (unsigned short)(u >> 16);
}

#define GLOBAL_LOAD_LDS16(gp, lp)                                                        \
    __builtin_amdgcn_global_load_lds((const __attribute__((address_space(1))) void*)(gp),\
                                     (__attribute__((address_space(3))) void*)(lp),      \
                                     16, 0, 0)

// x [B,T,D] f32 -> Hbf [T,B,D] bf16
__global__ __launch_bounds__(256) void k_convert_x(const float* __restrict__ x,
                                                   ushort_t* __restrict__ hbf) {
    int idx = (blockIdx.x * 256 + threadIdx.x) * 4;
    int d = idx & (D_ - 1);
    int t = (idx >> 10) & 3;
    int b = idx >> 12;
    const float4 v = *(const float4*)(x + idx);
    ushort4 o = { f2bf(v.x), f2bf(v.y), f2bf(v.z), f2bf(v.w) };
    *(ushort4*)(hbf + (size_t)t * B_ * D_ + (size_t)b * D_ + d) = o;
}

// W1,W2 [8, D, O] f32 -> W1t,W2t [8, O, D] bf16 in one launch (z: 0..7=W1, 8..15=W2)
__global__ __launch_bounds__(256) void k_transpose_w(const float* __restrict__ W1,
                                                     const float* __restrict__ W2,
                                                     ushort_t* __restrict__ W1t,
                                                     ushort_t* __restrict__ W2t) {
    __shared__ float tile[32][33];
    const int z = blockIdx.z;
    const float* src = (z < 8) ? (W1 + (size_t)z * D_ * D_) : (W2 + (size_t)(z - 8) * D_ * D_);
    ushort_t* dst = (z < 8) ? (W1t + (size_t)z * D_ * D_) : (W2t + (size_t)(z - 8) * D_ * D_);
    const int o0 = blockIdx.x * 32, d0 = blockIdx.y * 32;
    const int tx = threadIdx.x, ty = threadIdx.y;  // 32 x 8
#pragma unroll
    for (int j = 0; j < 4; ++j)
        tile[ty + 8 * j][tx] = src[(size_t)(d0 + ty + 8 * j) * D_ + o0 + tx];
    __syncthreads();
#pragma unroll
    for (int j = 0; j < 4; ++j)
        dst[(size_t)(o0 + ty + 8 * j) * D_ + d0 + tx] = f2bf(tile[tx][ty + 8 * j]);
}

// C[4096,1024] = relu(A * Bt^T + bias) [* scale], batched over tasks.
// 256x128 block tile (AI = 85 FLOP/staged-byte, above per-CU L2 staging ceiling
// at target util), 512 thr = 8 waves of 64x64, BK=32 double-buffered (48 KB LDS).
// A  : [T, 4096, 1024] bf16 (row-major, k contiguous)
// Bt : [T, 1024, 1024] bf16 (N-major: row n holds W[:,n], k contiguous)
template <bool OUT_BF16>
__global__ __launch_bounds__(512, 4) void k_gemm_bt(
    const ushort_t* __restrict__ A,
    const ushort_t* __restrict__ Bt,
    const float* __restrict__ bias,   // [T, 1024]
    void* __restrict__ out,           // [T, 4096, 1024]
    const float* __restrict__ inte)   // [T, E] or null
{
    // Swizzle: XCD = f%8 = 2t + (m&1) -> each XCD's L2 holds ONE task's Bt (2 MB)
    // plus that task's streamed A panels.
    const int f = blockIdx.x;           // 0..511
    const int xcd = f & 7;
    const int t = xcd >> 1;
    const int m_blk = ((f >> 6) << 1) | (xcd & 1);  // 0..15
    const int n_blk = (f >> 3) & 7;                 // 0..7
    const int m0 = m_blk * 256, n0 = n_blk * 128;

    const ushort_t* Ap = A + (size_t)t * B_ * D_;
    const ushort_t* Bp = Bt + (size_t)t * D_ * D_;
    const float* bp = bias + t * D_;

    __shared__ __align__(16) ushort_t As[2][256 * 32];   // 16 KB x2
    __shared__ __align__(16) ushort_t Bs[2][128 * 32];   //  8 KB x2

    const int tid = threadIdx.x;
    const int lane = tid & 63, wid = tid >> 6;           // 8 waves
    const int lr = lane & 15, quad = lane >> 4;
    const int wm = (wid & 3) * 64, wn = (wid >> 2) * 64; // 4x2 wave grid

    f32x4 acc[4][4] = {};

    // staging: A = 1024 16B-chunks (2 insts/thread), B = 512 chunks (1 inst)
    const int qa0 = wid * 64 + lane;        // 0..511
    const int qa1 = qa0 + 512;              // 512..1023
    const int qb  = qa0;
    const ushort_t* ga0 = Ap + (size_t)(m0 + (qa0 >> 2)) * D_ + (qa0 & 3) * 8;
    const ushort_t* ga1 = Ap + (size_t)(m0 + (qa1 >> 2)) * D_ + (qa1 & 3) * 8;
    const ushort_t* gb  = Bp + (size_t)(n0 + (qb  >> 2)) * D_ + (qb  & 3) * 8;

#define STAGE(k0, s)                                              \
    do {                                                          \
        GLOBAL_LOAD_LDS16(ga0 + (k0), As[s] + wid * 512);         \
        GLOBAL_LOAD_LDS16(ga1 + (k0), As[s] + 4096 + wid * 512);  \
        GLOBAL_LOAD_LDS16(gb  + (k0), Bs[s] + wid * 512);         \
    } while (0)

    STAGE(0, 0);
    int s = 0;
    for (int k0 = 0; k0 < D_; k0 += 32, s ^= 1) {
        __syncthreads();                    // drains buf-s loads
        if (k0 + 32 < D_) STAGE(k0 + 32, s ^ 1);  // in flight during compute below
        bf16x8 af[4], bfv[4];
#pragma unroll
        for (int mi = 0; mi < 4; ++mi)
            af[mi] = *(const bf16x8*)(As[s] + (wm + mi * 16 + lr) * 32 + quad * 8);
#pragma unroll
        for (int ni = 0; ni < 4; ++ni)
            bfv[ni] = *(const bf16x8*)(Bs[s] + (wn + ni * 16 + lr) * 32 + quad * 8);
#pragma unroll
        for (int mi = 0; mi < 4; ++mi)
#pragma unroll
            for (int ni = 0; ni < 4; ++ni)
                acc[mi][ni] = __builtin_amdgcn_mfma_f32_16x16x32_bf16(
                    af[mi], bfv[ni], acc[mi][ni], 0, 0, 0);
    }
#undef STAGE

    float scale = 1.0f;
    if (inte) {
        const float* ip = inte + t * E_;
        scale = ip[0] + ip[1] + ip[2] + ip[3];
    }
#pragma unroll
    for (int mi = 0; mi < 4; ++mi) {
#pragma unroll
        for (int ni = 0; ni < 4; ++ni) {
            const int gcol = n0 + wn + ni * 16 + lr;
            const float bv = bp[gcol];
#pragma unroll
            for (int r = 0; r < 4; ++r) {
                const int grow = m0 + wm + mi * 16 + quad * 4 + r;
                float v = acc[mi][ni][r] + bv;
                v = fmaxf(v, 0.0f) * scale;
                const size_t off = (size_t)t * B_ * D_ + (size_t)grow * D_ + gcol;
                if (OUT_BF16) ((ushort_t*)out)[off] = f2bf(v);
                else          ((float*)out)[off] = v;
            }
        }
    }
}

// gate + combine: one block per batch row b
template <bool FINAL>
__global__ __launch_bounds__(256) void k_gate_combine(
    const float* __restrict__ teo,  // [T, B, D] f32
    const float* __restrict__ Wg,   // [D, T] f32
    const float* __restrict__ bg,   // [T] f32
    void* __restrict__ out)         // FINAL: f32 [B,T,D]; else bf16 [T,B,D]
{
    const int b = blockIdx.x;
    const int tid = threadIdx.x;
    const int d0 = tid * 4;

    float4 tv[4];
#pragma unroll
    for (int t = 0; t < 4; ++t)
        tv[t] = *(const float4*)(teo + (size_t)t * B_ * D_ + (size_t)b * D_ + d0);
    float4 wg[4];
#pragma unroll
    for (int i = 0; i < 4; ++i)
        wg[i] = *(const float4*)(Wg + (size_t)(d0 + i) * 4);

    float p[16];
#pragma unroll
    for (int t = 0; t < 4; ++t) {
        const float* tvp = (const float*)&tv[t];
#pragma unroll
        for (int k = 0; k < 4; ++k) {
            p[t * 4 + k] = tvp[0] * ((const float*)&wg[0])[k]
                         + tvp[1] * ((const float*)&wg[1])[k]
                         + tvp[2] * ((const float*)&wg[2])[k]
                         + tvp[3] * ((const float*)&wg[3])[k];
        }
    }
#pragma unroll
    for (int i = 0; i < 16; ++i) {
        float v = p[i];
        v += __shfl_xor(v, 1, 64);
        v += __shfl_xor(v, 2, 64);
        v += __shfl_xor(v, 4, 64);
        v += __shfl_xor(v, 8, 64);
        p[i] = v;
    }
    __shared__ float red[16][16];
    __shared__ float fin[16];
    const int grp = tid >> 4;
    if ((tid & 15) == 0) {
#pragma unroll
        for (int i = 0; i < 16; ++i) red[grp][i] = p[i];
    }
    __syncthreads();
    if (tid < 16) {
        float v = 0.0f;
#pragma unroll
        for (int g = 0; g < 16; ++g) v += red[g][tid];
        fin[tid] = v;
    }
    __syncthreads();

    float g[4][4];
#pragma unroll
    for (int t = 0; t < 4; ++t) {
        float lg[4];
#pragma unroll
        for (int k = 0; k < 4; ++k)
            lg[k] = fin[t * 4 + k] + bg[k];
        float mx = fmaxf(fmaxf(lg[0], lg[1]), fmaxf(lg[2], lg[3]));
        float e0 = __expf(lg[0] - mx), e1 = __expf(lg[1] - mx);
        float e2 = __expf(lg[2] - mx), e3 = __expf(lg[3] - mx);
        float inv = 1.0f / (e0 + e1 + e2 + e3);
        g[t][0] = e0 * inv; g[t][1] = e1 * inv; g[t][2] = e2 * inv; g[t][3] = e3 * inv;
    }
#pragma unroll
    for (int t = 0; t < 4; ++t) {
        float o[4];
#pragma unroll
        for (int i = 0; i < 4; ++i) {
            o[i] = g[t][0] * ((const float*)&tv[0])[i]
                 + g[t][1] * ((const float*)&tv[1])[i]
                 + g[t][2] * ((const float*)&tv[2])[i]
                 + g[t][3] * ((const float*)&tv[3])[i]
                 + ((const float*)&tv[t])[i];
        }
        if (FINAL) {
            float4 ov = { o[0], o[1], o[2], o[3] };
            *(float4*)((float*)out + (size_t)b * T_ * D_ + (size_t)t * D_ + d0) = ov;
        } else {
            ushort4 ov = { f2bf(o[0]), f2bf(o[1]), f2bf(o[2]), f2bf(o[3]) };
            *(ushort4*)((ushort_t*)out + (size_t)t * B_ * D_ + (size_t)b * D_ + d0) = ov;
        }
    }
}

extern "C" void kernel_launch(void* const* d_in, const int* in_sizes, int n_in,
                              void* d_out, int out_size, void* d_ws, size_t ws_size,
                              hipStream_t stream) {
    const float* x    = (const float*)d_in[0];
    const float* W1   = (const float*)d_in[1];
    const float* b1   = (const float*)d_in[2];
    const float* W2   = (const float*)d_in[3];
    const float* b2   = (const float*)d_in[4];
    const float* inte = (const float*)d_in[5];
    const float* Wg   = (const float*)d_in[6];
    const float* bg   = (const float*)d_in[7];

    char* ws = (char*)d_ws;
    // ws layout (bytes): W1t 32M | W2t 32M | Hbf 32M | T1bf 32M | Teo 64M = 192 MiB
    ushort_t* W1t  = (ushort_t*)(ws);
    ushort_t* W2t  = (ushort_t*)(ws + 33554432);
    ushort_t* Hbf  = (ushort_t*)(ws + 67108864);
    ushort_t* T1bf = (ushort_t*)(ws + 100663296);
    float*    Teo  = (float*)   (ws + 134217728);

    k_convert_x<<<dim3(B_ * T_ * D_ / 1024), 256, 0, stream>>>(x, Hbf);
    k_transpose_w<<<dim3(D_ / 32, D_ / 32, 16), dim3(32, 8), 0, stream>>>(W1, W2, W1t, W2t);

    for (int l = 0; l < 2; ++l) {
        const size_t wOff = (size_t)l * T_ * D_ * D_;
        k_gemm_bt<true ><<<dim3(512), 512, 0, stream>>>(Hbf, W1t + wOff, b1 + l * T_ * D_,
                                                        (void*)T1bf, nullptr);
        k_gemm_bt<false><<<dim3(512), 512, 0, stream>>>(T1bf, W2t + wOff, b2 + l * T_ * D_,
                                                        (void*)Teo, inte + l * T_ * E_);
        if (l == 0)
            k_gate_combine<false><<<dim3(B_), 256, 0, stream>>>(
                Teo, Wg + l * D_ * T_, bg + l * T_, (void*)Hbf);
        else
            k_gate_combine<true ><<<dim3(B_), 256, 0, stream>>>(
                Teo, Wg + l * D_ * T_, bg + l * T_, (void*)d_out);
    }
}